// Round 1
// baseline (1216.352 us; speedup 1.0000x reference)
//
#include <hip/hip_runtime.h>
#include <hip/hip_bf16.h>

// ---------- types ----------
typedef __attribute__((ext_vector_type(8))) short bf16x8;   // 8 bf16 in 4 VGPRs
typedef __attribute__((ext_vector_type(4))) float f32x4;

#define MFMA_BF16(a, b, c) __builtin_amdgcn_mfma_f32_16x16x32_bf16((a), (b), (c), 0, 0, 0)

static __device__ __forceinline__ unsigned short f2bf(float f) {
  unsigned int u = __builtin_bit_cast(unsigned int, f);
  u += 0x7FFF + ((u >> 16) & 1);   // RNE
  return (unsigned short)(u >> 16);
}

// ---------- weight layout in d_ws (bf16 elements) ----------
enum : int {
  OFF_W0  = 0,        // [256][64]   (63 -> 64 pad)
  OFF_W1  = 16384,    // [256][256]
  OFF_W2  = 81920,
  OFF_W3  = 147456,
  OFF_W4  = 212992,   // [256][320]  (319 -> 320 pad)
  OFF_W5  = 294912,
  OFF_W6  = 360448,
  OFF_W7  = 425984,
  OFF_WF  = 491520,   // [256][256]
  OFF_WC1 = 557056,   // [128][288]  (283 -> 288 pad)
  OFF_WS  = 593920,   // [16][256]   (1 row -> 16, rows 1..15 zero)
  OFF_WC2 = 598016,   // [16][128]   (3 rows -> 16)
  W_TOTAL = 600064
};

struct Seg { const float* src; int rows_src, kin, kpad, rows_out, off; };
struct SegArgs { Seg s[12]; };

__global__ void convert_weights(SegArgs args, unsigned short* __restrict__ dst) {
  int idx = blockIdx.x * 256 + threadIdx.x;
  #pragma unroll
  for (int i = 0; i < 12; i++) {
    const Seg sg = args.s[i];
    const int sz = sg.rows_out * sg.kpad;
    if (idx < sz) {
      const int n = idx / sg.kpad;
      const int k = idx - n * sg.kpad;
      float v = (n < sg.rows_src && k < sg.kin) ? sg.src[n * sg.kin + k] : 0.0f;
      dst[sg.off + idx] = f2bf(v);
      return;
    }
    idx -= sz;
  }
}

// ---------- GEMM helpers ----------
// MFMA 16x16x32 bf16 layouts (verified m89):
//   A[m][k]: m = lane&15, k = (lane>>4)*8 + j   (16B contiguous per lane)
//   B[k][n]: n = lane&15, k = (lane>>4)*8 + j   (reads W[n][k] row-major)
//   D[m][n]: n = lane&15, m = (lane>>4)*4 + reg

template<int MF, int NF>
static __device__ __forceinline__ void zero_acc(f32x4 (&acc)[MF][NF]) {
  #pragma unroll
  for (int mi = 0; mi < MF; mi++)
    #pragma unroll
    for (int nf = 0; nf < NF; nf++)
      acc[mi][nf] = (f32x4){0.f, 0.f, 0.f, 0.f};
}

template<int MF, int NF>
static __device__ __forceinline__ void gemm_acc(
    f32x4 (&acc)[MF][NF],
    const unsigned short* __restrict__ aLds, int aStride, int mBase, int ak0,
    const unsigned short* __restrict__ wG, int wStride, int nBase, int wk0,
    int klen)
{
  const int lane = threadIdx.x & 63;
  const int lr   = lane & 15;
  const int lq8  = (lane >> 4) * 8;

  auto loadB = [&](bf16x8 (&d)[NF], int kk) {
    #pragma unroll
    for (int nf = 0; nf < NF; nf++)
      d[nf] = *(const bf16x8*)(wG + (nBase + nf * 16 + lr) * wStride + wk0 + kk + lq8);
  };
  auto loadA = [&](bf16x8 (&d)[MF], int kk) {
    #pragma unroll
    for (int mi = 0; mi < MF; mi++)
      d[mi] = *(const bf16x8*)(aLds + (mBase + mi * 16 + lr) * aStride + ak0 + kk + lq8);
  };
  auto domfma = [&](bf16x8 (&a)[MF], bf16x8 (&b)[NF]) {
    #pragma unroll
    for (int mi = 0; mi < MF; mi++)
      #pragma unroll
      for (int nf = 0; nf < NF; nf++)
        acc[mi][nf] = MFMA_BF16(a[mi], b[nf], acc[mi][nf]);
  };

  bf16x8 b0[NF], a0[MF], b1[NF], a1[MF];
  loadB(b0, 0); loadA(a0, 0);
  int kk = 0;
  for (; kk + 32 < klen; kk += 64) {          // 2-deep static double buffer
    loadB(b1, kk + 32); loadA(a1, kk + 32);
    domfma(a0, b0);
    if (kk + 64 < klen) { loadB(b0, kk + 64); loadA(a0, kk + 64); }
    domfma(a1, b1);
  }
  if (kk < klen) domfma(a0, b0);              // odd number of k-steps
}

template<int MF, int NF, bool RELU>
static __device__ __forceinline__ void store_act(
    const f32x4 (&acc)[MF][NF], const float* __restrict__ bias, int nBase,
    unsigned short* __restrict__ outLds, int outStride)
{
  const int lane = threadIdx.x & 63;
  const int lr   = lane & 15;
  const int lq4  = (lane >> 4) * 4;
  #pragma unroll
  for (int nf = 0; nf < NF; nf++) {
    const int n = nBase + nf * 16 + lr;
    const float bv = bias[n];
    #pragma unroll
    for (int mi = 0; mi < MF; mi++) {
      #pragma unroll
      for (int r = 0; r < 4; r++) {
        float v = acc[mi][nf][r] + bv;
        if (RELU) v = fmaxf(v, 0.0f);
        outLds[(mi * 16 + lq4 + r) * outStride + n] = f2bf(v);
      }
    }
  }
}

// ---------- fused NeRF kernel: 64 rows / block, 4 waves ----------
__global__ __launch_bounds__(256, 2) void nerf_main(
    const float* __restrict__ enc_pos, const float* __restrict__ enc_dir,
    const unsigned short* __restrict__ Wt,
    const float* __restrict__ b0, const float* __restrict__ b1,
    const float* __restrict__ b2, const float* __restrict__ b3,
    const float* __restrict__ b4, const float* __restrict__ b5,
    const float* __restrict__ b6, const float* __restrict__ b7,
    const float* __restrict__ bfb, const float* __restrict__ bsb,
    const float* __restrict__ bc1, const float* __restrict__ bc2,
    float* __restrict__ out)
{
  __shared__ __align__(16) unsigned short bufA[64 * 264];
  __shared__ __align__(16) unsigned short bufB[64 * 264];
  __shared__ __align__(16) unsigned short posb[64 * 72];   // enc_pos, later enc_dir

  const int tid  = threadIdx.x;
  const int wave = tid >> 6;
  const int lane = tid & 63;
  const int lr   = lane & 15;
  const int lq   = lane >> 4;
  const int row0 = blockIdx.x * 64;

  // stage enc_pos -> posb bf16, cols 0..62, col 63 zero (pad for K=64)
  for (int i = tid; i < 64 * 63; i += 256) {
    int r = i / 63, c = i - r * 63;
    posb[r * 72 + c] = f2bf(enc_pos[(size_t)(row0 + r) * 63 + c]);
  }
  if (tid < 64) posb[tid * 72 + 63] = 0;
  __syncthreads();

  f32x4 acc[4][4];

  // L0: posb(K=64) -> bufA
  zero_acc(acc);
  gemm_acc<4, 4>(acc, posb, 72, 0, 0, Wt + OFF_W0, 64, wave * 64, 0, 64);
  store_act<4, 4, true>(acc, b0, wave * 64, bufA, 264);
  __syncthreads();
  // L1: A -> B
  zero_acc(acc);
  gemm_acc<4, 4>(acc, bufA, 264, 0, 0, Wt + OFF_W1, 256, wave * 64, 0, 256);
  store_act<4, 4, true>(acc, b1, wave * 64, bufB, 264);
  __syncthreads();
  // L2: B -> A
  zero_acc(acc);
  gemm_acc<4, 4>(acc, bufB, 264, 0, 0, Wt + OFF_W2, 256, wave * 64, 0, 256);
  store_act<4, 4, true>(acc, b2, wave * 64, bufA, 264);
  __syncthreads();
  // L3: A -> B
  zero_acc(acc);
  gemm_acc<4, 4>(acc, bufA, 264, 0, 0, Wt + OFF_W3, 256, wave * 64, 0, 256);
  store_act<4, 4, true>(acc, b3, wave * 64, bufB, 264);
  __syncthreads();
  // L4 (skip concat, virtual): [bufB | posb] (K=256+64) -> bufA
  zero_acc(acc);
  gemm_acc<4, 4>(acc, bufB, 264, 0, 0, Wt + OFF_W4, 320, wave * 64, 0, 256);
  gemm_acc<4, 4>(acc, posb, 72, 0, 0, Wt + OFF_W4, 320, wave * 64, 256, 64);
  store_act<4, 4, true>(acc, b4, wave * 64, bufA, 264);
  __syncthreads();
  // L5: A -> B
  zero_acc(acc);
  gemm_acc<4, 4>(acc, bufA, 264, 0, 0, Wt + OFF_W5, 256, wave * 64, 0, 256);
  store_act<4, 4, true>(acc, b5, wave * 64, bufB, 264);
  __syncthreads();
  // L6: B -> A
  zero_acc(acc);
  gemm_acc<4, 4>(acc, bufB, 264, 0, 0, Wt + OFF_W6, 256, wave * 64, 0, 256);
  store_act<4, 4, true>(acc, b6, wave * 64, bufA, 264);
  __syncthreads();
  // L7: A -> B   (h7 lives in bufB)
  zero_acc(acc);
  gemm_acc<4, 4>(acc, bufA, 264, 0, 0, Wt + OFF_W7, 256, wave * 64, 0, 256);
  store_act<4, 4, true>(acc, b7, wave * 64, bufB, 264);
  __syncthreads();

  // stage enc_dir -> posb (posb is dead after L4; everyone is past L7 barrier)
  for (int i = tid; i < 64 * 27; i += 256) {
    int r = i / 27, c = i - r * 27;
    posb[r * 72 + c] = f2bf(enc_dir[(size_t)(row0 + r) * 27 + c]);
  }
  for (int i = tid; i < 64 * 5; i += 256) {
    int r = i / 5, c = 27 + (i - (i / 5) * 5);
    posb[r * 72 + c] = 0;
  }

  // sigma = h7 @ Ws^T + bs  (Ws padded to 16 rows; only n==0 valid)
  {
    f32x4 sacc[1][1];
    zero_acc(sacc);
    gemm_acc<1, 1>(sacc, bufB, 264, wave * 16, 0, Wt + OFF_WS, 256, 0, 0, 256);
    if (lr == 0) {
      float bv = bsb[0];
      #pragma unroll
      for (int r = 0; r < 4; r++)
        out[(size_t)(row0 + wave * 16 + lq * 4 + r) * 4 + 3] = sacc[0][0][r] + bv;
    }
  }

  // feature = h7 @ Wf^T + bf (no relu): bufB -> bufA
  zero_acc(acc);
  gemm_acc<4, 4>(acc, bufB, 264, 0, 0, Wt + OFF_WF, 256, wave * 64, 0, 256);
  store_act<4, 4, false>(acc, bfb, wave * 64, bufA, 264);
  __syncthreads();   // covers feature store + enc_dir staging

  // color_hidden = relu([feature | enc_dir] @ Wc1^T + bc1): -> bufB (128 cols)
  {
    f32x4 cacc[4][2];
    zero_acc(cacc);
    gemm_acc<4, 2>(cacc, bufA, 264, 0, 0, Wt + OFF_WC1, 288, wave * 32, 0, 256);
    gemm_acc<4, 2>(cacc, posb, 72, 0, 0, Wt + OFF_WC1, 288, wave * 32, 256, 32);
    store_act<4, 2, true>(cacc, bc1, wave * 32, bufB, 264);
  }
  __syncthreads();

  // color_raw = color_hidden @ Wc2^T + bc2 (Wc2 padded to 16 rows; n<3 valid)
  {
    f32x4 cacc[1][1];
    zero_acc(cacc);
    gemm_acc<1, 1>(cacc, bufB, 264, wave * 16, 0, Wt + OFF_WC2, 128, 0, 0, 128);
    if (lr < 3) {
      float bv = bc2[lr];
      #pragma unroll
      for (int r = 0; r < 4; r++)
        out[(size_t)(row0 + wave * 16 + lq * 4 + r) * 4 + lr] = cacc[0][0][r] + bv;
    }
  }
}

// ---------- launcher ----------
extern "C" void kernel_launch(void* const* d_in, const int* in_sizes, int n_in,
                              void* d_out, int out_size, void* d_ws, size_t ws_size,
                              hipStream_t stream) {
  const float* enc_pos = (const float*)d_in[0];
  const float* enc_dir = (const float*)d_in[1];
  unsigned short* wbf  = (unsigned short*)d_ws;

  SegArgs sa;
  // W0..W7
  sa.s[0]  = { (const float*)d_in[2],  256, 63,  64,  256, OFF_W0  };
  sa.s[1]  = { (const float*)d_in[4],  256, 256, 256, 256, OFF_W1  };
  sa.s[2]  = { (const float*)d_in[6],  256, 256, 256, 256, OFF_W2  };
  sa.s[3]  = { (const float*)d_in[8],  256, 256, 256, 256, OFF_W3  };
  sa.s[4]  = { (const float*)d_in[10], 256, 319, 320, 256, OFF_W4  };
  sa.s[5]  = { (const float*)d_in[12], 256, 256, 256, 256, OFF_W5  };
  sa.s[6]  = { (const float*)d_in[14], 256, 256, 256, 256, OFF_W6  };
  sa.s[7]  = { (const float*)d_in[16], 256, 256, 256, 256, OFF_W7  };
  sa.s[8]  = { (const float*)d_in[18], 256, 256, 256, 256, OFF_WF  };
  sa.s[9]  = { (const float*)d_in[22], 128, 283, 288, 128, OFF_WC1 };
  sa.s[10] = { (const float*)d_in[20], 1,   256, 256, 16,  OFF_WS  };
  sa.s[11] = { (const float*)d_in[24], 3,   128, 128, 16,  OFF_WC2 };

  convert_weights<<<W_TOTAL / 256, 256, 0, stream>>>(sa, wbf);

  const int N = in_sizes[0] / 63;          // 524288
  const int blocks = N / 64;               // 8192
  nerf_main<<<blocks, 256, 0, stream>>>(
      enc_pos, enc_dir, wbf,
      (const float*)d_in[3],  (const float*)d_in[5],
      (const float*)d_in[7],  (const float*)d_in[9],
      (const float*)d_in[11], (const float*)d_in[13],
      (const float*)d_in[15], (const float*)d_in[17],
      (const float*)d_in[19], (const float*)d_in[21],
      (const float*)d_in[23], (const float*)d_in[25],
      (float*)d_out);
}